// Round 13
// baseline (224.469 us; speedup 1.0000x reference)
//
#include <hip/hip_runtime.h>
#include <hip/hip_bf16.h>

#define HW   4096

typedef __bf16 bf_t;
typedef __bf16 bf8_t __attribute__((ext_vector_type(8)));
typedef float  f4_t  __attribute__((ext_vector_type(4)));
typedef int    i4_t  __attribute__((ext_vector_type(4)));

// Static device workspace (element offsets into g_ws, in floats):
#define OFF_A    0              // 2*50*HW NCHW offset maps
#define OFF_B    409600         // 2*98*HW
#define A1_F32   1212416        // NHWC fp32 [b][4096][64] = 524288 each
#define B1_F32   1736704
#define A2_F32   2260992
#define B2_F32   2785280
#define XA_F32   3309568
#define XB_F32   3833856
#define XA_HI    4358144        // bf16 NHWC = 262144 floats each
#define XA_LO    4620288
#define XB_HI    4882432
#define XB_LO    5144576
#define A1_HI    5406720
#define A1_LO    5668864
#define B1_HI    5931008
#define B1_LO    6193152
#define AW_A1    6455296        // conv weight packs (bf16 A-frag)
#define AW_B1    6464512
#define AW_A2    6515712
#define AW_B2    6566912
#define DW_A1    6767616        // depthwise weights transposed [KK][64]
#define DW_B1    6768192
#define DW_A2    6769792
#define DW_B2    6771392
#define WS_TOT   6774528

__device__ __align__(16) float g_ws[WS_TOT];

__device__ __forceinline__ bf8_t bf8_zero() {
    bf8_t v;
#pragma unroll
    for (int j = 0; j < 8; ++j) v[j] = (bf_t)0.f;
    return v;
}

// ---------------------------------------------------------------------------
// Weight prep helpers (range-dispatched).
// ---------------------------------------------------------------------------
__device__ __forceinline__ void prep_wA_dev(const float* wg, int aw_off,
                                            int Cout, int K, int NCOT, int lb) {
    const int KK = K * K;
    const int total = KK * NCOT * 128;
    const int idx = lb * 256 + threadIdx.x;
    if (idx >= total) return;
    bf_t* aw = (bf_t*)(g_ws + aw_off);
    int lane = idx & 63;
    int kh   = (idx >> 6) & 1;
    int cot  = (idx >> 7) % NCOT;
    int tap  = idx / (128 * NCOT);
    int co   = cot * 16 + (lane & 15);
    int ci0  = kh * 32 + (lane >> 4) * 8;
    bf8_t v;
#pragma unroll
    for (int j = 0; j < 8; ++j) {
        float f = (co < Cout) ? wg[(co * 64 + ci0 + j) * KK + tap] : 0.f;
        v[j] = (bf_t)f;
    }
    *(bf8_t*)&aw[(long)idx * 8] = v;
}

__device__ __forceinline__ void prep_dwT_dev(const float* w, int dst_off,
                                             int KK, int lb) {
    const int idx = lb * 256 + threadIdx.x;
    if (idx < KK * 64) {
        int c = idx & 63, kk = idx >> 6;
        g_ws[dst_off + kk * 64 + c] = w[c * KK + kk];
    }
}

// ---------------------------------------------------------------------------
// Kernel 1: all weight prep (blocks 0..334) + x -> NHWC fp32 / bf16 hi-lo
// split (blocks 335..1358). x is genuine fp32 (R12 lesson: lo != 0).
// ---------------------------------------------------------------------------
__global__ __launch_bounds__(256) void prep_split_kernel(
    const float* __restrict__ x,
    const float* cv0_off_w, const float* c0_off_w,
    const float* cvs_off_w, const float* cs_off_w,
    const float* cv0_w, const float* c0_w,
    const float* cvs_w, const float* cs_w)
{
    __shared__ float lds[16 * 68];
    const int bi = blockIdx.x;
    if (bi < 335) {
        if      (bi < 9)   prep_wA_dev(cv0_off_w, AW_A1, 18, 3, 2, bi);
        else if (bi < 59)  prep_wA_dev(c0_off_w,  AW_B1, 50, 5, 4, bi - 9);
        else if (bi < 109) prep_wA_dev(cvs_off_w, AW_A2, 50, 5, 4, bi - 59);
        else if (bi < 305) prep_wA_dev(cs_off_w,  AW_B2, 98, 7, 8, bi - 109);
        else if (bi < 308) prep_dwT_dev(cv0_w, DW_A1, 9,  bi - 305);
        else if (bi < 315) prep_dwT_dev(c0_w,  DW_B1, 25, bi - 308);
        else if (bi < 322) prep_dwT_dev(cvs_w, DW_A2, 25, bi - 315);
        else               prep_dwT_dev(cs_w,  DW_B2, 49, bi - 322);
        return;
    }
    const int s  = bi - 335;
    const int b  = s & 1;
    const int br = (s >> 1) & 1;
    const int p0 = (s >> 2) * 16;
    const float* sb = x + (long)b * (128 * HW) + (long)br * (64 * HW);
    bf_t*  dhi = (bf_t*)(g_ws + (br ? XB_HI : XA_HI));
    bf_t*  dlo = (bf_t*)(g_ws + (br ? XB_LO : XA_LO));
    float* df  = g_ws + (br ? XB_F32 : XA_F32);
    const int t = threadIdx.x;
    {
        const int px = t & 15;
        const int c0 = t >> 4;
#pragma unroll
        for (int pass = 0; pass < 4; ++pass) {
            int ci = c0 + pass * 16;
            lds[px * 68 + ci] = sb[ci * HW + p0 + px];
        }
    }
    __syncthreads();
    if (t < 128) {
        int px = t >> 3, q = t & 7;
        bf8_t vh, vl;
        f4_t  f0, f1;
#pragma unroll
        for (int j = 0; j < 8; ++j) {
            float a = lds[px * 68 + q * 8 + j];
            bf_t hcast = (bf_t)a;
            vh[j] = hcast;
            vl[j] = (bf_t)(a - (float)hcast);
            if (j < 4) f0[j] = a; else f1[j - 4] = a;
        }
        long base = (((long)b * 4096 + p0 + px) * 64) + q * 8;
        *(bf8_t*)&dhi[base] = vh;
        *(bf8_t*)&dlo[base] = vl;
        *(f4_t*)&df[base]     = f0;
        *(f4_t*)&df[base + 4] = f1;
    }
}

// ---------------------------------------------------------------------------
// MFMA implicit-GEMM conv body (hi/lo split input), dynamic-LDS version.
// ---------------------------------------------------------------------------
template<int K, int DIL, int PAD, int NCOT, int CPG>
__device__ __forceinline__ void mfma_conv_dev(
    int bx, int by, bf_t* smem,
    int hi_off, int lo_off, int aw_off, const float* __restrict__ bias,
    int dst_off, int Cout)
{
    constexpr int COLS = 64 + 2 * PAD;
    const bf_t* shi = (const bf_t*)(g_ws + hi_off);
    const bf_t* slo = (const bf_t*)(g_ws + lo_off);
    const bf_t* aw  = (const bf_t*)(g_ws + aw_off);
    float* dst = g_ws + dst_off;
    bf_t* lds0 = smem;
    bf_t* lds1 = smem + COLS * 72;

    const int t    = threadIdx.x;
    const int lane = t & 63;
    const int wv   = t >> 6;
    const int b    = bx >> 6;
    const int h    = bx & 63;
    const int ct0  = by * CPG;

    const int n0 = lane & 15;
    const int kq = lane >> 4;

    f4_t acc[CPG];
#pragma unroll
    for (int i = 0; i < CPG; ++i) acc[i] = (f4_t){0.f, 0.f, 0.f, 0.f};

    for (int ky = 0; ky < K; ++ky) {
        const int ih = h - PAD + ky * DIL;
        __syncthreads();
        if ((unsigned)ih < 64u) {
            const long rowb = ((long)b * 4096 + ih * 64) * 64;
            for (int c = t; c < COLS * 8; c += 256) {
                int col = c >> 3, q = c & 7;
                int iw = col - PAD;
                bf8_t vh, vl;
                if ((unsigned)iw < 64u) {
                    vh = *(const bf8_t*)&shi[rowb + iw * 64 + q * 8];
                    vl = *(const bf8_t*)&slo[rowb + iw * 64 + q * 8];
                } else { vh = bf8_zero(); vl = bf8_zero(); }
                *(bf8_t*)&lds0[col * 72 + q * 8] = vh;
                *(bf8_t*)&lds1[col * 72 + q * 8] = vl;
            }
        } else {
            bf8_t z = bf8_zero();
            for (int c = t; c < COLS * 8; c += 256) {
                int col = c >> 3, q = c & 7;
                *(bf8_t*)&lds0[col * 72 + q * 8] = z;
                *(bf8_t*)&lds1[col * 72 + q * 8] = z;
            }
        }
        __syncthreads();
#pragma unroll
        for (int kx = 0; kx < K; ++kx) {
            const int tap = ky * K + kx;
            bf8_t afr[CPG][2];
#pragma unroll
            for (int ct = 0; ct < CPG; ++ct)
#pragma unroll
                for (int kh = 0; kh < 2; ++kh)
                    afr[ct][kh] = *(const bf8_t*)
                        &aw[((((long)tap * NCOT + ct0 + ct) * 2 + kh) * 64 + lane) * 8];
            const int colb = (wv * 16 + n0 + kx * DIL) * 72;
#pragma unroll
            for (int kh = 0; kh < 2; ++kh) {
                const bf8_t bh = *(const bf8_t*)&lds0[colb + kh * 32 + kq * 8];
                const bf8_t bl = *(const bf8_t*)&lds1[colb + kh * 32 + kq * 8];
#pragma unroll
                for (int ct = 0; ct < CPG; ++ct) {
                    acc[ct] = __builtin_amdgcn_mfma_f32_16x16x32_bf16(
                        afr[ct][kh], bh, acc[ct], 0, 0, 0);
                    acc[ct] = __builtin_amdgcn_mfma_f32_16x16x32_bf16(
                        afr[ct][kh], bl, acc[ct], 0, 0, 0);
                }
            }
        }
    }

    const int w = wv * 16 + n0;
#pragma unroll
    for (int ct = 0; ct < CPG; ++ct) {
#pragma unroll
        for (int r = 0; r < 4; ++r) {
            int co = (ct0 + ct) * 16 + kq * 4 + r;
            if (co < Cout)
                dst[((long)b * Cout + co) * HW + h * 64 + w] = acc[ct][r] + bias[co];
        }
    }
}

// Kernel 2: stage-1 convs, k3 (256) / k5 (512) interleaved mod 3.
__global__ __launch_bounds__(256) void conv_s1_kernel(
    const float* __restrict__ biasA, const float* __restrict__ biasB)
{
    extern __shared__ __align__(16) bf_t smem1[];
    const int bi = blockIdx.x;
    const int g = bi / 3, r = bi % 3;
    if (r == 0)
        mfma_conv_dev<3, 1, 1, 2, 1>(g & 127, g >> 7, smem1,
                                     XA_HI, XA_LO, AW_A1, biasA, OFF_A, 18);
    else {
        const int s = 2 * g + (r - 1);
        mfma_conv_dev<5, 1, 2, 4, 1>(s & 127, s >> 7, smem1,
                                     XB_HI, XB_LO, AW_B1, biasB, OFF_B, 50);
    }
}

// Kernel 4: stage-2 convs, k5 / k7 interleaved even/odd. smem 23616 B.
__global__ __launch_bounds__(256) void conv_s2_kernel(
    const float* __restrict__ biasA, const float* __restrict__ biasB)
{
    extern __shared__ __align__(16) bf_t smem2[];
    const int bi = blockIdx.x;
    const int s = bi >> 1;
    if ((bi & 1) == 0)
        mfma_conv_dev<5, 3, 6, 4, 1>(s & 127, s >> 7, smem2,
                                     A1_HI, A1_LO, AW_A2, biasA, OFF_A, 50);
    else
        mfma_conv_dev<7, 3, 9, 8, 2>(s & 127, s >> 7, smem2,
                                     B1_HI, B1_LO, AW_B2, biasB, OFF_B, 98);
}

// ---------------------------------------------------------------------------
// Fused deformable sampler: phase A computes this block's 4*KK bilinear
// records into LDS; phase B (lane = channel, wave = pixel) consumes them as
// wave-uniform LDS broadcasts + coalesced corner gathers. readfirstlane on
// the wave-uniform pixel id gives an SGPR image base -> saddr-form gathers.
// ---------------------------------------------------------------------------
template<int KK, int WRITE_HILO>
__device__ __forceinline__ void sample_fused_dev(
    int bx, float* recs, int src_off, int off_off, int dwt_off,
    int dst_off, int hi_off, int lo_off, int K, int pad, int dil)
{
    const int t   = threadIdx.x;
    const int pgi = ((bx & 7) << 8) | (bx >> 3);   // XCD-contiguous chunks

    // phase A: records for this block's 4 pixels
    for (int rec = t; rec < 4 * KK; rec += 256) {
        const int wv = rec & 3;
        const int kk = rec >> 2;
        const int pg = pgi * 4 + wv;
        const int b  = pg >> 12;
        const int p  = pg & 4095;
        const int h  = p >> 6, w = p & 63;
        const float oy = g_ws[off_off + ((long)(b * 2 * KK + 2 * kk)) * HW + p];
        const float ox = g_ws[off_off + ((long)(b * 2 * KK + 2 * kk + 1)) * HW + p];
        const float py = oy + (float)(h - pad + (kk / K) * dil);
        const float px = ox + (float)(w - pad + (kk % K) * dil);
        const float fy = floorf(py), fx = floorf(px);
        const float ly = py - fy,    lx = px - fx;
        const int y0 = (int)fy, x0 = (int)fx;
        const int y1 = y0 + 1,  x1 = x0 + 1;
        const float vy0 = ((unsigned)y0 < 64u) ? 1.f : 0.f;
        const float vy1 = ((unsigned)y1 < 64u) ? 1.f : 0.f;
        const float vx0 = ((unsigned)x0 < 64u) ? 1.f : 0.f;
        const float vx1 = ((unsigned)x1 < 64u) ? 1.f : 0.f;
        const float w00 = (1.f - ly) * (1.f - lx) * vy0 * vx0;
        const float w01 = (1.f - ly) * lx         * vy0 * vx1;
        const float w10 = ly         * (1.f - lx) * vy1 * vx0;
        const float w11 = ly         * lx         * vy1 * vx1;
        const int y0c = min(max(y0, 0), 63), y1c = min(max(y1, 0), 63);
        const int x0c = min(max(x0, 0), 63), x1c = min(max(x1, 0), 63);
        const int i00 = (y0c * 64 + x0c) * 256, i01 = (y0c * 64 + x1c) * 256;
        const int i10 = (y1c * 64 + x0c) * 256, i11 = (y1c * 64 + x1c) * 256;
        float* rp = &recs[rec * 8];
        *(f4_t*)rp       = (f4_t){w00, w01, w10, w11};
        *(i4_t*)(rp + 4) = (i4_t){i00, i01, i10, i11};
    }
    __syncthreads();

    // phase B
    const int c  = t & 63;
    const int wv = t >> 6;
    const int pg = __builtin_amdgcn_readfirstlane(pgi * 4 + wv);  // wave-uniform
    const int b  = pg >> 12;
    const int p  = pg & 4095;
    const int cb = c << 2;

    const char* sb = (const char*)(g_ws + src_off + ((long)b << 18));
    const float* wtp = g_ws + dwt_off + c;

    float acc = 0.f;
#pragma unroll 8
    for (int kk = 0; kk < KK; ++kk) {
        const float* rp = &recs[(kk * 4 + wv) * 8];
        const f4_t wq = *(const f4_t*)rp;
        const i4_t iq = *(const i4_t*)(rp + 4);
        const float v00 = *(const float*)(sb + (iq.x + cb));
        const float v01 = *(const float*)(sb + (iq.y + cb));
        const float v10 = *(const float*)(sb + (iq.z + cb));
        const float v11 = *(const float*)(sb + (iq.w + cb));
        const float val = wq.x * v00 + wq.y * v01 + wq.z * v10 + wq.w * v11;
        acc = fmaf(wtp[kk * 64], val, acc);
    }

    const long ob = ((long)b * 4096 + p) * 64 + c;
    g_ws[dst_off + ob] = acc;
    if (WRITE_HILO) {
        bf_t h16 = (bf_t)acc;
        ((bf_t*)(g_ws + hi_off))[ob] = h16;
        ((bf_t*)(g_ws + lo_off))[ob] = (bf_t)(acc - (float)h16);
    }
}

template<int KA, int KB, int WRITE_HILO>
__global__ __launch_bounds__(256) void sample_kernel(
    int srcA, int offA, int dwtA, int dstA, int hiA, int loA, int padA, int dilA,
    int srcB, int offB, int dwtB, int dstB, int hiB, int loB, int padB, int dilB)
{
    __shared__ __align__(16) float recs[4 * 49 * 8];
    const int bx = blockIdx.x;
    const int s = bx >> 1;
    if ((bx & 1) == 0)       // interleaved: flattens A/B duration imbalance
        sample_fused_dev<KA * KA, WRITE_HILO>(s, recs, srcA, offA, dwtA,
                                              dstA, hiA, loA, KA, padA, dilA);
    else
        sample_fused_dev<KB * KB, WRITE_HILO>(s, recs, srcB, offB, dwtB,
                                              dstB, hiB, loB, KB, padB, dilB);
}

// ---------------------------------------------------------------------------
// Kernel 6: per-branch 1x1 conv (+bias), then out = x * result.
// ---------------------------------------------------------------------------
__global__ __launch_bounds__(256) void final_kernel(
    const float* __restrict__ x,
    int aA_off, int aB_off,
    const float* __restrict__ w1, const float* __restrict__ b1,
    const float* __restrict__ w2, const float* __restrict__ b2,
    float* __restrict__ out)
{
    __shared__ float atile[64 * 65];
    __shared__ float wlds[64 * 32];
    const int t  = threadIdx.x;
    const int p0 = blockIdx.x * 64;
    const int by = blockIdx.y;
    const int b  = blockIdx.z;
    const bool brB  = (by >> 1) != 0;
    const int  cbase = (by & 1) * 32;
    const float* a  = g_ws + (brB ? aB_off : aA_off) + (long)b * (4096 * 64);
    const float* wg = brB ? w2 : w1;
    const float* bg = brB ? b2 : b1;

    {
        const int ci = t & 63;
        const int pxg = (t >> 6) * 16;
#pragma unroll
        for (int i = 0; i < 16; ++i) {
            int px = pxg + i;
            atile[px * 65 + ci] = a[(long)(p0 + px) * 64 + ci];
        }
    }
    for (int e = t; e < 2048; e += 256) {
        int col = e & 31, ci = e >> 5;
        wlds[ci * 32 + col] = wg[(cbase + col) * 64 + ci];
    }
    __syncthreads();

    const int px  = t & 63;
    const int cog = t >> 6;
    float acc[8] = {0, 0, 0, 0, 0, 0, 0, 0};
    for (int ci = 0; ci < 64; ++ci) {
        const float av = atile[px * 65 + ci];
        const float* wr = &wlds[ci * 32 + cog * 8];
#pragma unroll
        for (int j = 0; j < 8; ++j) acc[j] = fmaf(av, wr[j], acc[j]);
    }

    const int p = p0 + px;
#pragma unroll
    for (int j = 0; j < 8; ++j) {
        const int co = cbase + cog * 8 + j;
        const int cg = (brB ? 64 : 0) + co;
        const long o = ((long)b * 128 + cg) * HW + p;
        out[o] = (acc[j] + bg[co]) * x[o];
    }
}

// ---------------------------------------------------------------------------
extern "C" void kernel_launch(void* const* d_in, const int* in_sizes, int n_in,
                              void* d_out, int out_size, void* d_ws, size_t ws_size,
                              hipStream_t stream) {
    const float* x         = (const float*)d_in[0];
    const float* cv0_off_w = (const float*)d_in[1];
    const float* cv0_off_b = (const float*)d_in[2];
    const float* cv0_w     = (const float*)d_in[3];
    const float* cvs_off_w = (const float*)d_in[4];
    const float* cvs_off_b = (const float*)d_in[5];
    const float* cvs_w     = (const float*)d_in[6];
    const float* c0_off_w  = (const float*)d_in[7];
    const float* c0_off_b  = (const float*)d_in[8];
    const float* c0_w      = (const float*)d_in[9];
    const float* cs_off_w  = (const float*)d_in[10];
    const float* cs_off_b  = (const float*)d_in[11];
    const float* cs_w      = (const float*)d_in[12];
    const float* conv1_w   = (const float*)d_in[13];
    const float* conv1_b   = (const float*)d_in[14];
    const float* conv2_w   = (const float*)d_in[15];
    const float* conv2_b   = (const float*)d_in[16];
    float* out = (float*)d_out;
    (void)d_ws; (void)ws_size;

    // 1: weight prep + x NHWC/hi-lo split
    prep_split_kernel<<<dim3(1359), 256, 0, stream>>>(
        x, cv0_off_w, c0_off_w, cvs_off_w, cs_off_w, cv0_w, c0_w, cvs_w, cs_w);

    // 2: stage-1 offset convs (k3 + k5, hi/lo, interleaved)
    conv_s1_kernel<<<dim3(768), 256, 19584, stream>>>(cv0_off_b, c0_off_b);

    // 3: stage-1 fused precompute+sampling (+ hi/lo emit)
    sample_kernel<3, 5, 1><<<dim3(4096), 256, 0, stream>>>(
        XA_F32, OFF_A, DW_A1, A1_F32, A1_HI, A1_LO, 1, 1,
        XB_F32, OFF_B, DW_B1, B1_F32, B1_HI, B1_LO, 2, 1);

    // 4: stage-2 offset convs (k5 + k7, hi/lo, interleaved)
    conv_s2_kernel<<<dim3(1024), 256, 23616, stream>>>(cvs_off_b, cs_off_b);

    // 5: stage-2 fused precompute+sampling
    sample_kernel<5, 7, 0><<<dim3(4096), 256, 0, stream>>>(
        A1_F32, OFF_A, DW_A2, A2_F32, 0, 0, 6, 3,
        B1_F32, OFF_B, DW_B2, B2_F32, 0, 0, 9, 3);

    // 6: 1x1 convs + gating multiply
    final_kernel<<<dim3(64, 4, 2), 256, 0, stream>>>(
        x, A2_F32, B2_F32, conv1_w, conv1_b, conv2_w, conv2_b, out);
}

// Round 14
// 218.627 us; speedup vs baseline: 1.0267x; 1.0267x over previous
//
#include <hip/hip_runtime.h>
#include <hip/hip_bf16.h>

#define HW   4096

typedef __bf16 bf_t;
typedef __bf16 bf8_t __attribute__((ext_vector_type(8)));
typedef float  f4_t  __attribute__((ext_vector_type(4)));
typedef int    i4_t  __attribute__((ext_vector_type(4)));

// Static device workspace (element offsets into g_ws, in floats):
#define OFF_A    0              // 2*50*HW NCHW offset maps
#define OFF_B    409600         // 2*98*HW
#define A1_F32   1212416        // NHWC fp32 [b][4096][64] = 524288 each
#define B1_F32   1736704
#define A2_F32   2260992
#define B2_F32   2785280
#define XA_F32   3309568
#define XB_F32   3833856
#define XA_HI    4358144        // bf16 NHWC = 262144 floats each
#define XA_LO    4620288
#define XB_HI    4882432
#define XB_LO    5144576
#define A1_HI    5406720
#define A1_LO    5668864
#define B1_HI    5931008
#define B1_LO    6193152
#define AW_A1    6455296        // conv weight packs (bf16 A-frag)
#define AW_B1    6464512
#define AW_A2    6515712
#define AW_B2    6566912
#define DW_A1    6767616        // depthwise weights transposed [KK][64]
#define DW_B1    6768192
#define DW_A2    6769792
#define DW_B2    6771392
#define WS_TOT   6774528

__device__ __align__(16) float g_ws[WS_TOT];

__device__ __forceinline__ bf8_t bf8_zero() {
    bf8_t v;
#pragma unroll
    for (int j = 0; j < 8; ++j) v[j] = (bf_t)0.f;
    return v;
}

// ---------------------------------------------------------------------------
// Weight prep helpers (range-dispatched).
// ---------------------------------------------------------------------------
__device__ __forceinline__ void prep_wA_dev(const float* wg, int aw_off,
                                            int Cout, int K, int NCOT, int lb) {
    const int KK = K * K;
    const int total = KK * NCOT * 128;
    const int idx = lb * 256 + threadIdx.x;
    if (idx >= total) return;
    bf_t* aw = (bf_t*)(g_ws + aw_off);
    int lane = idx & 63;
    int kh   = (idx >> 6) & 1;
    int cot  = (idx >> 7) % NCOT;
    int tap  = idx / (128 * NCOT);
    int co   = cot * 16 + (lane & 15);
    int ci0  = kh * 32 + (lane >> 4) * 8;
    bf8_t v;
#pragma unroll
    for (int j = 0; j < 8; ++j) {
        float f = (co < Cout) ? wg[(co * 64 + ci0 + j) * KK + tap] : 0.f;
        v[j] = (bf_t)f;
    }
    *(bf8_t*)&aw[(long)idx * 8] = v;
}

__device__ __forceinline__ void prep_dwT_dev(const float* w, int dst_off,
                                             int KK, int lb) {
    const int idx = lb * 256 + threadIdx.x;
    if (idx < KK * 64) {
        int c = idx & 63, kk = idx >> 6;
        g_ws[dst_off + kk * 64 + c] = w[c * KK + kk];
    }
}

// ---------------------------------------------------------------------------
// Kernel 1: all weight prep (blocks 0..334) + x -> NHWC fp32 / bf16 hi-lo
// split (blocks 335..1358). x is genuine fp32 (R12 lesson: lo != 0).
// ---------------------------------------------------------------------------
__global__ __launch_bounds__(256) void prep_split_kernel(
    const float* __restrict__ x,
    const float* cv0_off_w, const float* c0_off_w,
    const float* cvs_off_w, const float* cs_off_w,
    const float* cv0_w, const float* c0_w,
    const float* cvs_w, const float* cs_w)
{
    __shared__ float lds[16 * 68];
    const int bi = blockIdx.x;
    if (bi < 335) {
        if      (bi < 9)   prep_wA_dev(cv0_off_w, AW_A1, 18, 3, 2, bi);
        else if (bi < 59)  prep_wA_dev(c0_off_w,  AW_B1, 50, 5, 4, bi - 9);
        else if (bi < 109) prep_wA_dev(cvs_off_w, AW_A2, 50, 5, 4, bi - 59);
        else if (bi < 305) prep_wA_dev(cs_off_w,  AW_B2, 98, 7, 8, bi - 109);
        else if (bi < 308) prep_dwT_dev(cv0_w, DW_A1, 9,  bi - 305);
        else if (bi < 315) prep_dwT_dev(c0_w,  DW_B1, 25, bi - 308);
        else if (bi < 322) prep_dwT_dev(cvs_w, DW_A2, 25, bi - 315);
        else               prep_dwT_dev(cs_w,  DW_B2, 49, bi - 322);
        return;
    }
    const int s  = bi - 335;
    const int b  = s & 1;
    const int br = (s >> 1) & 1;
    const int p0 = (s >> 2) * 16;
    const float* sb = x + (long)b * (128 * HW) + (long)br * (64 * HW);
    bf_t*  dhi = (bf_t*)(g_ws + (br ? XB_HI : XA_HI));
    bf_t*  dlo = (bf_t*)(g_ws + (br ? XB_LO : XA_LO));
    float* df  = g_ws + (br ? XB_F32 : XA_F32);
    const int t = threadIdx.x;
    {
        const int px = t & 15;
        const int c0 = t >> 4;
#pragma unroll
        for (int pass = 0; pass < 4; ++pass) {
            int ci = c0 + pass * 16;
            lds[px * 68 + ci] = sb[ci * HW + p0 + px];
        }
    }
    __syncthreads();
    if (t < 128) {
        int px = t >> 3, q = t & 7;
        bf8_t vh, vl;
        f4_t  f0, f1;
#pragma unroll
        for (int j = 0; j < 8; ++j) {
            float a = lds[px * 68 + q * 8 + j];
            bf_t hcast = (bf_t)a;
            vh[j] = hcast;
            vl[j] = (bf_t)(a - (float)hcast);
            if (j < 4) f0[j] = a; else f1[j - 4] = a;
        }
        long base = (((long)b * 4096 + p0 + px) * 64) + q * 8;
        *(bf8_t*)&dhi[base] = vh;
        *(bf8_t*)&dlo[base] = vl;
        *(f4_t*)&df[base]     = f0;
        *(f4_t*)&df[base + 4] = f1;
    }
}

// ---------------------------------------------------------------------------
// MFMA implicit-GEMM conv body (hi/lo split input), dynamic-LDS version.
// ---------------------------------------------------------------------------
template<int K, int DIL, int PAD, int NCOT, int CPG>
__device__ __forceinline__ void mfma_conv_dev(
    int bx, int by, bf_t* smem,
    int hi_off, int lo_off, int aw_off, const float* __restrict__ bias,
    int dst_off, int Cout)
{
    constexpr int COLS = 64 + 2 * PAD;
    const bf_t* shi = (const bf_t*)(g_ws + hi_off);
    const bf_t* slo = (const bf_t*)(g_ws + lo_off);
    const bf_t* aw  = (const bf_t*)(g_ws + aw_off);
    float* dst = g_ws + dst_off;
    bf_t* lds0 = smem;
    bf_t* lds1 = smem + COLS * 72;

    const int t    = threadIdx.x;
    const int lane = t & 63;
    const int wv   = t >> 6;
    const int b    = bx >> 6;
    const int h    = bx & 63;
    const int ct0  = by * CPG;

    const int n0 = lane & 15;
    const int kq = lane >> 4;

    f4_t acc[CPG];
#pragma unroll
    for (int i = 0; i < CPG; ++i) acc[i] = (f4_t){0.f, 0.f, 0.f, 0.f};

    for (int ky = 0; ky < K; ++ky) {
        const int ih = h - PAD + ky * DIL;
        __syncthreads();
        if ((unsigned)ih < 64u) {
            const long rowb = ((long)b * 4096 + ih * 64) * 64;
            for (int c = t; c < COLS * 8; c += 256) {
                int col = c >> 3, q = c & 7;
                int iw = col - PAD;
                bf8_t vh, vl;
                if ((unsigned)iw < 64u) {
                    vh = *(const bf8_t*)&shi[rowb + iw * 64 + q * 8];
                    vl = *(const bf8_t*)&slo[rowb + iw * 64 + q * 8];
                } else { vh = bf8_zero(); vl = bf8_zero(); }
                *(bf8_t*)&lds0[col * 72 + q * 8] = vh;
                *(bf8_t*)&lds1[col * 72 + q * 8] = vl;
            }
        } else {
            bf8_t z = bf8_zero();
            for (int c = t; c < COLS * 8; c += 256) {
                int col = c >> 3, q = c & 7;
                *(bf8_t*)&lds0[col * 72 + q * 8] = z;
                *(bf8_t*)&lds1[col * 72 + q * 8] = z;
            }
        }
        __syncthreads();
#pragma unroll
        for (int kx = 0; kx < K; ++kx) {
            const int tap = ky * K + kx;
            bf8_t afr[CPG][2];
#pragma unroll
            for (int ct = 0; ct < CPG; ++ct)
#pragma unroll
                for (int kh = 0; kh < 2; ++kh)
                    afr[ct][kh] = *(const bf8_t*)
                        &aw[((((long)tap * NCOT + ct0 + ct) * 2 + kh) * 64 + lane) * 8];
            const int colb = (wv * 16 + n0 + kx * DIL) * 72;
#pragma unroll
            for (int kh = 0; kh < 2; ++kh) {
                const bf8_t bh = *(const bf8_t*)&lds0[colb + kh * 32 + kq * 8];
                const bf8_t bl = *(const bf8_t*)&lds1[colb + kh * 32 + kq * 8];
#pragma unroll
                for (int ct = 0; ct < CPG; ++ct) {
                    acc[ct] = __builtin_amdgcn_mfma_f32_16x16x32_bf16(
                        afr[ct][kh], bh, acc[ct], 0, 0, 0);
                    acc[ct] = __builtin_amdgcn_mfma_f32_16x16x32_bf16(
                        afr[ct][kh], bl, acc[ct], 0, 0, 0);
                }
            }
        }
    }

    const int w = wv * 16 + n0;
#pragma unroll
    for (int ct = 0; ct < CPG; ++ct) {
#pragma unroll
        for (int r = 0; r < 4; ++r) {
            int co = (ct0 + ct) * 16 + kq * 4 + r;
            if (co < Cout)
                dst[((long)b * Cout + co) * HW + h * 64 + w] = acc[ct][r] + bias[co];
        }
    }
}

// Kernel 2: stage-1 convs, k3 (256) / k5 (512) interleaved mod 3.
__global__ __launch_bounds__(256) void conv_s1_kernel(
    const float* __restrict__ biasA, const float* __restrict__ biasB)
{
    extern __shared__ __align__(16) bf_t smem1[];
    const int bi = blockIdx.x;
    const int g = bi / 3, r = bi % 3;
    if (r == 0)
        mfma_conv_dev<3, 1, 1, 2, 1>(g & 127, g >> 7, smem1,
                                     XA_HI, XA_LO, AW_A1, biasA, OFF_A, 18);
    else {
        const int s = 2 * g + (r - 1);
        mfma_conv_dev<5, 1, 2, 4, 1>(s & 127, s >> 7, smem1,
                                     XB_HI, XB_LO, AW_B1, biasB, OFF_B, 50);
    }
}

// Kernel 4: stage-2 convs, k5 / k7 interleaved even/odd. smem 23616 B.
__global__ __launch_bounds__(256) void conv_s2_kernel(
    const float* __restrict__ biasA, const float* __restrict__ biasB)
{
    extern __shared__ __align__(16) bf_t smem2[];
    const int bi = blockIdx.x;
    const int s = bi >> 1;
    if ((bi & 1) == 0)
        mfma_conv_dev<5, 3, 6, 4, 1>(s & 127, s >> 7, smem2,
                                     A1_HI, A1_LO, AW_A2, biasA, OFF_A, 50);
    else
        mfma_conv_dev<7, 3, 9, 8, 2>(s & 127, s >> 7, smem2,
                                     B1_HI, B1_LO, AW_B2, biasB, OFF_B, 98);
}

// ---------------------------------------------------------------------------
// Fused deformable sampler (R10-optimal phase B): phase A computes this
// block's 4*KK bilinear records into LDS; phase B (lane = channel, wave =
// pixel) consumes them as wave-uniform LDS broadcasts + coalesced corner
// gathers off a per-lane base pointer (VGPR 16, occ ~66% — measured best).
// ---------------------------------------------------------------------------
template<int KK, int WRITE_HILO>
__device__ __forceinline__ void sample_fused_dev(
    int bx, float* recs, int src_off, int off_off, int dwt_off,
    int dst_off, int hi_off, int lo_off, int K, int pad, int dil)
{
    const int t   = threadIdx.x;
    const int pgi = ((bx & 7) << 8) | (bx >> 3);   // XCD-contiguous chunks

    // phase A: records for this block's 4 pixels
    for (int rec = t; rec < 4 * KK; rec += 256) {
        const int wv = rec & 3;
        const int kk = rec >> 2;
        const int pg = pgi * 4 + wv;
        const int b  = pg >> 12;
        const int p  = pg & 4095;
        const int h  = p >> 6, w = p & 63;
        const float oy = g_ws[off_off + ((long)(b * 2 * KK + 2 * kk)) * HW + p];
        const float ox = g_ws[off_off + ((long)(b * 2 * KK + 2 * kk + 1)) * HW + p];
        const float py = oy + (float)(h - pad + (kk / K) * dil);
        const float px = ox + (float)(w - pad + (kk % K) * dil);
        const float fy = floorf(py), fx = floorf(px);
        const float ly = py - fy,    lx = px - fx;
        const int y0 = (int)fy, x0 = (int)fx;
        const int y1 = y0 + 1,  x1 = x0 + 1;
        const float vy0 = ((unsigned)y0 < 64u) ? 1.f : 0.f;
        const float vy1 = ((unsigned)y1 < 64u) ? 1.f : 0.f;
        const float vx0 = ((unsigned)x0 < 64u) ? 1.f : 0.f;
        const float vx1 = ((unsigned)x1 < 64u) ? 1.f : 0.f;
        const float w00 = (1.f - ly) * (1.f - lx) * vy0 * vx0;
        const float w01 = (1.f - ly) * lx         * vy0 * vx1;
        const float w10 = ly         * (1.f - lx) * vy1 * vx0;
        const float w11 = ly         * lx         * vy1 * vx1;
        const int y0c = min(max(y0, 0), 63), y1c = min(max(y1, 0), 63);
        const int x0c = min(max(x0, 0), 63), x1c = min(max(x1, 0), 63);
        const int i00 = (y0c * 64 + x0c) * 256, i01 = (y0c * 64 + x1c) * 256;
        const int i10 = (y1c * 64 + x0c) * 256, i11 = (y1c * 64 + x1c) * 256;
        float* rp = &recs[rec * 8];
        *(f4_t*)rp       = (f4_t){w00, w01, w10, w11};
        *(i4_t*)(rp + 4) = (i4_t){i00, i01, i10, i11};
    }
    __syncthreads();

    // phase B (exact R10 form)
    const int c  = t & 63;
    const int wv = t >> 6;
    const int pg = pgi * 4 + wv;
    const int b  = pg >> 12;
    const int p  = pg & 4095;

    const char* sb = (const char*)(g_ws + src_off + ((long)b << 18)) + (c << 2);
    const float* wtp = g_ws + dwt_off + c;

    float acc = 0.f;
#pragma unroll 8
    for (int kk = 0; kk < KK; ++kk) {
        const float* rp = &recs[(kk * 4 + wv) * 8];
        const f4_t wq = *(const f4_t*)rp;
        const i4_t iq = *(const i4_t*)(rp + 4);
        const float v00 = *(const float*)(sb + iq.x);
        const float v01 = *(const float*)(sb + iq.y);
        const float v10 = *(const float*)(sb + iq.z);
        const float v11 = *(const float*)(sb + iq.w);
        const float val = wq.x * v00 + wq.y * v01 + wq.z * v10 + wq.w * v11;
        acc = fmaf(wtp[kk * 64], val, acc);
    }

    const long ob = ((long)b * 4096 + p) * 64 + c;
    g_ws[dst_off + ob] = acc;
    if (WRITE_HILO) {
        bf_t h16 = (bf_t)acc;
        ((bf_t*)(g_ws + hi_off))[ob] = h16;
        ((bf_t*)(g_ws + lo_off))[ob] = (bf_t)(acc - (float)h16);
    }
}

template<int KA, int KB, int WRITE_HILO>
__global__ __launch_bounds__(256) void sample_kernel(
    int srcA, int offA, int dwtA, int dstA, int hiA, int loA, int padA, int dilA,
    int srcB, int offB, int dwtB, int dstB, int hiB, int loB, int padB, int dilB)
{
    __shared__ __align__(16) float recs[4 * 49 * 8];
    const int bx = blockIdx.x;
    const int s = bx >> 1;
    if ((bx & 1) == 0)       // interleaved: flattens A/B duration imbalance
        sample_fused_dev<KA * KA, WRITE_HILO>(s, recs, srcA, offA, dwtA,
                                              dstA, hiA, loA, KA, padA, dilA);
    else
        sample_fused_dev<KB * KB, WRITE_HILO>(s, recs, srcB, offB, dwtB,
                                              dstB, hiB, loB, KB, padB, dilB);
}

// ---------------------------------------------------------------------------
// Kernel 6: per-branch 1x1 conv (+bias), then out = x * result.
// ---------------------------------------------------------------------------
__global__ __launch_bounds__(256) void final_kernel(
    const float* __restrict__ x,
    int aA_off, int aB_off,
    const float* __restrict__ w1, const float* __restrict__ b1,
    const float* __restrict__ w2, const float* __restrict__ b2,
    float* __restrict__ out)
{
    __shared__ float atile[64 * 65];
    __shared__ float wlds[64 * 32];
    const int t  = threadIdx.x;
    const int p0 = blockIdx.x * 64;
    const int by = blockIdx.y;
    const int b  = blockIdx.z;
    const bool brB  = (by >> 1) != 0;
    const int  cbase = (by & 1) * 32;
    const float* a  = g_ws + (brB ? aB_off : aA_off) + (long)b * (4096 * 64);
    const float* wg = brB ? w2 : w1;
    const float* bg = brB ? b2 : b1;

    {
        const int ci = t & 63;
        const int pxg = (t >> 6) * 16;
#pragma unroll
        for (int i = 0; i < 16; ++i) {
            int px = pxg + i;
            atile[px * 65 + ci] = a[(long)(p0 + px) * 64 + ci];
        }
    }
    for (int e = t; e < 2048; e += 256) {
        int col = e & 31, ci = e >> 5;
        wlds[ci * 32 + col] = wg[(cbase + col) * 64 + ci];
    }
    __syncthreads();

    const int px  = t & 63;
    const int cog = t >> 6;
    float acc[8] = {0, 0, 0, 0, 0, 0, 0, 0};
    for (int ci = 0; ci < 64; ++ci) {
        const float av = atile[px * 65 + ci];
        const float* wr = &wlds[ci * 32 + cog * 8];
#pragma unroll
        for (int j = 0; j < 8; ++j) acc[j] = fmaf(av, wr[j], acc[j]);
    }

    const int p = p0 + px;
#pragma unroll
    for (int j = 0; j < 8; ++j) {
        const int co = cbase + cog * 8 + j;
        const int cg = (brB ? 64 : 0) + co;
        const long o = ((long)b * 128 + cg) * HW + p;
        out[o] = (acc[j] + bg[co]) * x[o];
    }
}

// ---------------------------------------------------------------------------
extern "C" void kernel_launch(void* const* d_in, const int* in_sizes, int n_in,
                              void* d_out, int out_size, void* d_ws, size_t ws_size,
                              hipStream_t stream) {
    const float* x         = (const float*)d_in[0];
    const float* cv0_off_w = (const float*)d_in[1];
    const float* cv0_off_b = (const float*)d_in[2];
    const float* cv0_w     = (const float*)d_in[3];
    const float* cvs_off_w = (const float*)d_in[4];
    const float* cvs_off_b = (const float*)d_in[5];
    const float* cvs_w     = (const float*)d_in[6];
    const float* c0_off_w  = (const float*)d_in[7];
    const float* c0_off_b  = (const float*)d_in[8];
    const float* c0_w      = (const float*)d_in[9];
    const float* cs_off_w  = (const float*)d_in[10];
    const float* cs_off_b  = (const float*)d_in[11];
    const float* cs_w      = (const float*)d_in[12];
    const float* conv1_w   = (const float*)d_in[13];
    const float* conv1_b   = (const float*)d_in[14];
    const float* conv2_w   = (const float*)d_in[15];
    const float* conv2_b   = (const float*)d_in[16];
    float* out = (float*)d_out;
    (void)d_ws; (void)ws_size;

    // 1: weight prep + x NHWC/hi-lo split
    prep_split_kernel<<<dim3(1359), 256, 0, stream>>>(
        x, cv0_off_w, c0_off_w, cvs_off_w, cs_off_w, cv0_w, c0_w, cvs_w, cs_w);

    // 2: stage-1 offset convs (k3 + k5, hi/lo, interleaved)
    conv_s1_kernel<<<dim3(768), 256, 19584, stream>>>(cv0_off_b, c0_off_b);

    // 3: stage-1 fused precompute+sampling (+ hi/lo emit)
    sample_kernel<3, 5, 1><<<dim3(4096), 256, 0, stream>>>(
        XA_F32, OFF_A, DW_A1, A1_F32, A1_HI, A1_LO, 1, 1,
        XB_F32, OFF_B, DW_B1, B1_F32, B1_HI, B1_LO, 2, 1);

    // 4: stage-2 offset convs (k5 + k7, hi/lo, interleaved)
    conv_s2_kernel<<<dim3(1024), 256, 23616, stream>>>(cvs_off_b, cs_off_b);

    // 5: stage-2 fused precompute+sampling
    sample_kernel<5, 7, 0><<<dim3(4096), 256, 0, stream>>>(
        A1_F32, OFF_A, DW_A2, A2_F32, 0, 0, 6, 3,
        B1_F32, OFF_B, DW_B2, B2_F32, 0, 0, 9, 3);

    // 6: 1x1 convs + gating multiply
    final_kernel<<<dim3(64, 4, 2), 256, 0, stream>>>(
        x, A2_F32, B2_F32, conv1_w, conv1_b, conv2_w, conv2_b, out);
}

// Round 15
// 201.608 us; speedup vs baseline: 1.1134x; 1.0844x over previous
//
#include <hip/hip_runtime.h>
#include <hip/hip_bf16.h>

#define HW   4096

typedef __bf16 bf_t;
typedef __bf16 bf8_t __attribute__((ext_vector_type(8)));
typedef float  f4_t  __attribute__((ext_vector_type(4)));
typedef int    i4_t  __attribute__((ext_vector_type(4)));

// Static device workspace (element offsets into g_ws, in floats):
#define OFF_A    0              // 2*50*HW NCHW offset maps
#define OFF_B    409600         // 2*98*HW
#define A1_F32   1212416        // NHWC fp32 [b][4096][64] = 524288 each
#define B1_F32   1736704
#define A2_F32   2260992
#define B2_F32   2785280
#define XA_F32   3309568
#define XB_F32   3833856
#define XA_HI    4358144        // bf16 NHWC = 262144 floats each
#define XA_LO    4620288
#define XB_HI    4882432
#define XB_LO    5144576
#define A1_HI    5406720
#define A1_LO    5668864
#define B1_HI    5931008
#define B1_LO    6193152
#define AW_A1    6455296        // conv weight packs (bf16 A-frag)
#define AW_B1    6464512
#define AW_A2    6515712
#define AW_B2    6566912
#define DW_A1    6767616        // depthwise weights transposed [KK][64]
#define DW_B1    6768192
#define DW_A2    6769792
#define DW_B2    6771392
#define WS_TOT   6774528

__device__ __align__(16) float g_ws[WS_TOT];

__device__ __forceinline__ bf8_t bf8_zero() {
    bf8_t v;
#pragma unroll
    for (int j = 0; j < 8; ++j) v[j] = (bf_t)0.f;
    return v;
}

// ---------------------------------------------------------------------------
// Weight prep helpers (range-dispatched).
// ---------------------------------------------------------------------------
__device__ __forceinline__ void prep_wA_dev(const float* wg, int aw_off,
                                            int Cout, int K, int NCOT, int lb) {
    const int KK = K * K;
    const int total = KK * NCOT * 128;
    const int idx = lb * 256 + threadIdx.x;
    if (idx >= total) return;
    bf_t* aw = (bf_t*)(g_ws + aw_off);
    int lane = idx & 63;
    int kh   = (idx >> 6) & 1;
    int cot  = (idx >> 7) % NCOT;
    int tap  = idx / (128 * NCOT);
    int co   = cot * 16 + (lane & 15);
    int ci0  = kh * 32 + (lane >> 4) * 8;
    bf8_t v;
#pragma unroll
    for (int j = 0; j < 8; ++j) {
        float f = (co < Cout) ? wg[(co * 64 + ci0 + j) * KK + tap] : 0.f;
        v[j] = (bf_t)f;
    }
    *(bf8_t*)&aw[(long)idx * 8] = v;
}

__device__ __forceinline__ void prep_dwT_dev(const float* w, int dst_off,
                                             int KK, int lb) {
    const int idx = lb * 256 + threadIdx.x;
    if (idx < KK * 64) {
        int c = idx & 63, kk = idx >> 6;
        g_ws[dst_off + kk * 64 + c] = w[c * KK + kk];
    }
}

// ---------------------------------------------------------------------------
// Kernel 1: all weight prep (blocks 0..334) + x -> NHWC fp32 / bf16 hi-lo
// split (blocks 335..1358).
// ---------------------------------------------------------------------------
__global__ __launch_bounds__(256) void prep_split_kernel(
    const float* __restrict__ x,
    const float* cv0_off_w, const float* c0_off_w,
    const float* cvs_off_w, const float* cs_off_w,
    const float* cv0_w, const float* c0_w,
    const float* cvs_w, const float* cs_w)
{
    __shared__ float lds[16 * 68];
    const int bi = blockIdx.x;
    if (bi < 335) {
        if      (bi < 9)   prep_wA_dev(cv0_off_w, AW_A1, 18, 3, 2, bi);
        else if (bi < 59)  prep_wA_dev(c0_off_w,  AW_B1, 50, 5, 4, bi - 9);
        else if (bi < 109) prep_wA_dev(cvs_off_w, AW_A2, 50, 5, 4, bi - 59);
        else if (bi < 305) prep_wA_dev(cs_off_w,  AW_B2, 98, 7, 8, bi - 109);
        else if (bi < 308) prep_dwT_dev(cv0_w, DW_A1, 9,  bi - 305);
        else if (bi < 315) prep_dwT_dev(c0_w,  DW_B1, 25, bi - 308);
        else if (bi < 322) prep_dwT_dev(cvs_w, DW_A2, 25, bi - 315);
        else               prep_dwT_dev(cs_w,  DW_B2, 49, bi - 322);
        return;
    }
    const int s  = bi - 335;
    const int b  = s & 1;
    const int br = (s >> 1) & 1;
    const int p0 = (s >> 2) * 16;
    const float* sb = x + (long)b * (128 * HW) + (long)br * (64 * HW);
    bf_t*  dhi = (bf_t*)(g_ws + (br ? XB_HI : XA_HI));
    bf_t*  dlo = (bf_t*)(g_ws + (br ? XB_LO : XA_LO));
    float* df  = g_ws + (br ? XB_F32 : XA_F32);
    const int t = threadIdx.x;
    {
        const int px = t & 15;
        const int c0 = t >> 4;
#pragma unroll
        for (int pass = 0; pass < 4; ++pass) {
            int ci = c0 + pass * 16;
            lds[px * 68 + ci] = sb[ci * HW + p0 + px];
        }
    }
    __syncthreads();
    if (t < 128) {
        int px = t >> 3, q = t & 7;
        bf8_t vh, vl;
        f4_t  f0, f1;
#pragma unroll
        for (int j = 0; j < 8; ++j) {
            float a = lds[px * 68 + q * 8 + j];
            bf_t hcast = (bf_t)a;
            vh[j] = hcast;
            vl[j] = (bf_t)(a - (float)hcast);
            if (j < 4) f0[j] = a; else f1[j - 4] = a;
        }
        long base = (((long)b * 4096 + p0 + px) * 64) + q * 8;
        *(bf8_t*)&dhi[base] = vh;
        *(bf8_t*)&dlo[base] = vl;
        *(f4_t*)&df[base]     = f0;
        *(f4_t*)&df[base + 4] = f1;
    }
}

// ---------------------------------------------------------------------------
// MFMA implicit-GEMM conv body (hi/lo split input), dynamic-LDS version.
// ---------------------------------------------------------------------------
template<int K, int DIL, int PAD, int NCOT, int CPG>
__device__ __forceinline__ void mfma_conv_dev(
    int bx, int by, bf_t* smem,
    int hi_off, int lo_off, int aw_off, const float* __restrict__ bias,
    int dst_off, int Cout)
{
    constexpr int COLS = 64 + 2 * PAD;
    const bf_t* shi = (const bf_t*)(g_ws + hi_off);
    const bf_t* slo = (const bf_t*)(g_ws + lo_off);
    const bf_t* aw  = (const bf_t*)(g_ws + aw_off);
    float* dst = g_ws + dst_off;
    bf_t* lds0 = smem;
    bf_t* lds1 = smem + COLS * 72;

    const int t    = threadIdx.x;
    const int lane = t & 63;
    const int wv   = t >> 6;
    const int b    = bx >> 6;
    const int h    = bx & 63;
    const int ct0  = by * CPG;

    const int n0 = lane & 15;
    const int kq = lane >> 4;

    f4_t acc[CPG];
#pragma unroll
    for (int i = 0; i < CPG; ++i) acc[i] = (f4_t){0.f, 0.f, 0.f, 0.f};

    for (int ky = 0; ky < K; ++ky) {
        const int ih = h - PAD + ky * DIL;
        __syncthreads();
        if ((unsigned)ih < 64u) {
            const long rowb = ((long)b * 4096 + ih * 64) * 64;
            for (int c = t; c < COLS * 8; c += 256) {
                int col = c >> 3, q = c & 7;
                int iw = col - PAD;
                bf8_t vh, vl;
                if ((unsigned)iw < 64u) {
                    vh = *(const bf8_t*)&shi[rowb + iw * 64 + q * 8];
                    vl = *(const bf8_t*)&slo[rowb + iw * 64 + q * 8];
                } else { vh = bf8_zero(); vl = bf8_zero(); }
                *(bf8_t*)&lds0[col * 72 + q * 8] = vh;
                *(bf8_t*)&lds1[col * 72 + q * 8] = vl;
            }
        } else {
            bf8_t z = bf8_zero();
            for (int c = t; c < COLS * 8; c += 256) {
                int col = c >> 3, q = c & 7;
                *(bf8_t*)&lds0[col * 72 + q * 8] = z;
                *(bf8_t*)&lds1[col * 72 + q * 8] = z;
            }
        }
        __syncthreads();
#pragma unroll
        for (int kx = 0; kx < K; ++kx) {
            const int tap = ky * K + kx;
            bf8_t afr[CPG][2];
#pragma unroll
            for (int ct = 0; ct < CPG; ++ct)
#pragma unroll
                for (int kh = 0; kh < 2; ++kh)
                    afr[ct][kh] = *(const bf8_t*)
                        &aw[((((long)tap * NCOT + ct0 + ct) * 2 + kh) * 64 + lane) * 8];
            const int colb = (wv * 16 + n0 + kx * DIL) * 72;
#pragma unroll
            for (int kh = 0; kh < 2; ++kh) {
                const bf8_t bh = *(const bf8_t*)&lds0[colb + kh * 32 + kq * 8];
                const bf8_t bl = *(const bf8_t*)&lds1[colb + kh * 32 + kq * 8];
#pragma unroll
                for (int ct = 0; ct < CPG; ++ct) {
                    acc[ct] = __builtin_amdgcn_mfma_f32_16x16x32_bf16(
                        afr[ct][kh], bh, acc[ct], 0, 0, 0);
                    acc[ct] = __builtin_amdgcn_mfma_f32_16x16x32_bf16(
                        afr[ct][kh], bl, acc[ct], 0, 0, 0);
                }
            }
        }
    }

    const int w = wv * 16 + n0;
#pragma unroll
    for (int ct = 0; ct < CPG; ++ct) {
#pragma unroll
        for (int r = 0; r < 4; ++r) {
            int co = (ct0 + ct) * 16 + kq * 4 + r;
            if (co < Cout)
                dst[((long)b * Cout + co) * HW + h * 64 + w] = acc[ct][r] + bias[co];
        }
    }
}

// Kernel 2: stage-1 convs (k3: blocks 0..255, k5: 256..767), sequential halves.
__global__ __launch_bounds__(256) void conv_s1_kernel(
    const float* __restrict__ biasA, const float* __restrict__ biasB)
{
    extern __shared__ __align__(16) bf_t smem1[];
    const int bi = blockIdx.x;
    if (bi < 256)
        mfma_conv_dev<3, 1, 1, 2, 1>(bi & 127, bi >> 7, smem1,
                                     XA_HI, XA_LO, AW_A1, biasA, OFF_A, 18);
    else {
        const int s = bi - 256;
        mfma_conv_dev<5, 1, 2, 4, 1>(s & 127, s >> 7, smem1,
                                     XB_HI, XB_LO, AW_B1, biasB, OFF_B, 50);
    }
}

// Kernel 4: stage-2 convs (k5: 0..511, k7: 512..1023), sequential halves.
__global__ __launch_bounds__(256) void conv_s2_kernel(
    const float* __restrict__ biasA, const float* __restrict__ biasB)
{
    extern __shared__ __align__(16) bf_t smem2[];
    const int bi = blockIdx.x;
    if (bi < 512)
        mfma_conv_dev<5, 3, 6, 4, 1>(bi & 127, bi >> 7, smem2,
                                     A1_HI, A1_LO, AW_A2, biasA, OFF_A, 50);
    else {
        const int s = bi - 512;
        mfma_conv_dev<7, 3, 9, 8, 2>(s & 127, s >> 7, smem2,
                                     B1_HI, B1_LO, AW_B2, biasB, OFF_B, 98);
    }
}

// ---------------------------------------------------------------------------
// Fused deformable sampler (R10-optimal, sequential-half dispatch): phase A
// computes this block's 4*KK bilinear records into LDS; phase B (lane =
// channel, wave = pixel) consumes them as wave-uniform LDS broadcasts +
// coalesced corner gathers off a per-lane base pointer.
// ---------------------------------------------------------------------------
template<int KK, int WRITE_HILO>
__device__ __forceinline__ void sample_fused_dev(
    int bx, float* recs, int src_off, int off_off, int dwt_off,
    int dst_off, int hi_off, int lo_off, int K, int pad, int dil)
{
    const int t   = threadIdx.x;
    const int pgi = ((bx & 7) << 8) | (bx >> 3);   // XCD-contiguous chunks

    // phase A: records for this block's 4 pixels
    for (int rec = t; rec < 4 * KK; rec += 256) {
        const int wv = rec & 3;
        const int kk = rec >> 2;
        const int pg = pgi * 4 + wv;
        const int b  = pg >> 12;
        const int p  = pg & 4095;
        const int h  = p >> 6, w = p & 63;
        const float oy = g_ws[off_off + ((long)(b * 2 * KK + 2 * kk)) * HW + p];
        const float ox = g_ws[off_off + ((long)(b * 2 * KK + 2 * kk + 1)) * HW + p];
        const float py = oy + (float)(h - pad + (kk / K) * dil);
        const float px = ox + (float)(w - pad + (kk % K) * dil);
        const float fy = floorf(py), fx = floorf(px);
        const float ly = py - fy,    lx = px - fx;
        const int y0 = (int)fy, x0 = (int)fx;
        const int y1 = y0 + 1,  x1 = x0 + 1;
        const float vy0 = ((unsigned)y0 < 64u) ? 1.f : 0.f;
        const float vy1 = ((unsigned)y1 < 64u) ? 1.f : 0.f;
        const float vx0 = ((unsigned)x0 < 64u) ? 1.f : 0.f;
        const float vx1 = ((unsigned)x1 < 64u) ? 1.f : 0.f;
        const float w00 = (1.f - ly) * (1.f - lx) * vy0 * vx0;
        const float w01 = (1.f - ly) * lx         * vy0 * vx1;
        const float w10 = ly         * (1.f - lx) * vy1 * vx0;
        const float w11 = ly         * lx         * vy1 * vx1;
        const int y0c = min(max(y0, 0), 63), y1c = min(max(y1, 0), 63);
        const int x0c = min(max(x0, 0), 63), x1c = min(max(x1, 0), 63);
        const int i00 = (y0c * 64 + x0c) * 256, i01 = (y0c * 64 + x1c) * 256;
        const int i10 = (y1c * 64 + x0c) * 256, i11 = (y1c * 64 + x1c) * 256;
        float* rp = &recs[rec * 8];
        *(f4_t*)rp       = (f4_t){w00, w01, w10, w11};
        *(i4_t*)(rp + 4) = (i4_t){i00, i01, i10, i11};
    }
    __syncthreads();

    // phase B (exact R10 form: VGPR 16, occ ~66% — measured best)
    const int c  = t & 63;
    const int wv = t >> 6;
    const int pg = pgi * 4 + wv;
    const int b  = pg >> 12;
    const int p  = pg & 4095;

    const char* sb = (const char*)(g_ws + src_off + ((long)b << 18)) + (c << 2);
    const float* wtp = g_ws + dwt_off + c;

    float acc = 0.f;
#pragma unroll 8
    for (int kk = 0; kk < KK; ++kk) {
        const float* rp = &recs[(kk * 4 + wv) * 8];
        const f4_t wq = *(const f4_t*)rp;
        const i4_t iq = *(const i4_t*)(rp + 4);
        const float v00 = *(const float*)(sb + iq.x);
        const float v01 = *(const float*)(sb + iq.y);
        const float v10 = *(const float*)(sb + iq.z);
        const float v11 = *(const float*)(sb + iq.w);
        const float val = wq.x * v00 + wq.y * v01 + wq.z * v10 + wq.w * v11;
        acc = fmaf(wtp[kk * 64], val, acc);
    }

    const long ob = ((long)b * 4096 + p) * 64 + c;
    g_ws[dst_off + ob] = acc;
    if (WRITE_HILO) {
        bf_t h16 = (bf_t)acc;
        ((bf_t*)(g_ws + hi_off))[ob] = h16;
        ((bf_t*)(g_ws + lo_off))[ob] = (bf_t)(acc - (float)h16);
    }
}

template<int KA, int KB, int WRITE_HILO>
__global__ __launch_bounds__(256) void sample_kernel(
    int srcA, int offA, int dwtA, int dstA, int hiA, int loA, int padA, int dilA,
    int srcB, int offB, int dwtB, int dstB, int hiB, int loB, int padB, int dilB)
{
    __shared__ __align__(16) float recs[4 * 49 * 8];
    const int bx = blockIdx.x;
    if (bx < 2048)        // sequential halves: best measured L2 behavior
        sample_fused_dev<KA * KA, WRITE_HILO>(bx, recs, srcA, offA, dwtA,
                                              dstA, hiA, loA, KA, padA, dilA);
    else
        sample_fused_dev<KB * KB, WRITE_HILO>(bx - 2048, recs, srcB, offB, dwtB,
                                              dstB, hiB, loB, KB, padB, dilB);
}

// ---------------------------------------------------------------------------
// Kernel 6: per-branch 1x1 conv (+bias), then out = x * result.
// ---------------------------------------------------------------------------
__global__ __launch_bounds__(256) void final_kernel(
    const float* __restrict__ x,
    int aA_off, int aB_off,
    const float* __restrict__ w1, const float* __restrict__ b1,
    const float* __restrict__ w2, const float* __restrict__ b2,
    float* __restrict__ out)
{
    __shared__ float atile[64 * 65];
    __shared__ float wlds[64 * 32];
    const int t  = threadIdx.x;
    const int p0 = blockIdx.x * 64;
    const int by = blockIdx.y;
    const int b  = blockIdx.z;
    const bool brB  = (by >> 1) != 0;
    const int  cbase = (by & 1) * 32;
    const float* a  = g_ws + (brB ? aB_off : aA_off) + (long)b * (4096 * 64);
    const float* wg = brB ? w2 : w1;
    const float* bg = brB ? b2 : b1;

    {
        const int ci = t & 63;
        const int pxg = (t >> 6) * 16;
#pragma unroll
        for (int i = 0; i < 16; ++i) {
            int px = pxg + i;
            atile[px * 65 + ci] = a[(long)(p0 + px) * 64 + ci];
        }
    }
    for (int e = t; e < 2048; e += 256) {
        int col = e & 31, ci = e >> 5;
        wlds[ci * 32 + col] = wg[(cbase + col) * 64 + ci];
    }
    __syncthreads();

    const int px  = t & 63;
    const int cog = t >> 6;
    float acc[8] = {0, 0, 0, 0, 0, 0, 0, 0};
    for (int ci = 0; ci < 64; ++ci) {
        const float av = atile[px * 65 + ci];
        const float* wr = &wlds[ci * 32 + cog * 8];
#pragma unroll
        for (int j = 0; j < 8; ++j) acc[j] = fmaf(av, wr[j], acc[j]);
    }

    const int p = p0 + px;
#pragma unroll
    for (int j = 0; j < 8; ++j) {
        const int co = cbase + cog * 8 + j;
        const int cg = (brB ? 64 : 0) + co;
        const long o = ((long)b * 128 + cg) * HW + p;
        out[o] = (acc[j] + bg[co]) * x[o];
    }
}

// ---------------------------------------------------------------------------
extern "C" void kernel_launch(void* const* d_in, const int* in_sizes, int n_in,
                              void* d_out, int out_size, void* d_ws, size_t ws_size,
                              hipStream_t stream) {
    const float* x         = (const float*)d_in[0];
    const float* cv0_off_w = (const float*)d_in[1];
    const float* cv0_off_b = (const float*)d_in[2];
    const float* cv0_w     = (const float*)d_in[3];
    const float* cvs_off_w = (const float*)d_in[4];
    const float* cvs_off_b = (const float*)d_in[5];
    const float* cvs_w     = (const float*)d_in[6];
    const float* c0_off_w  = (const float*)d_in[7];
    const float* c0_off_b  = (const float*)d_in[8];
    const float* c0_w      = (const float*)d_in[9];
    const float* cs_off_w  = (const float*)d_in[10];
    const float* cs_off_b  = (const float*)d_in[11];
    const float* cs_w      = (const float*)d_in[12];
    const float* conv1_w   = (const float*)d_in[13];
    const float* conv1_b   = (const float*)d_in[14];
    const float* conv2_w   = (const float*)d_in[15];
    const float* conv2_b   = (const float*)d_in[16];
    float* out = (float*)d_out;
    (void)d_ws; (void)ws_size;

    // 1: weight prep + x NHWC/hi-lo split
    prep_split_kernel<<<dim3(1359), 256, 0, stream>>>(
        x, cv0_off_w, c0_off_w, cvs_off_w, cs_off_w, cv0_w, c0_w, cvs_w, cs_w);

    // 2: stage-1 offset convs (k3 + k5)
    conv_s1_kernel<<<dim3(768), 256, 19584, stream>>>(cv0_off_b, c0_off_b);

    // 3: stage-1 fused precompute+sampling (+ hi/lo emit)
    sample_kernel<3, 5, 1><<<dim3(4096), 256, 0, stream>>>(
        XA_F32, OFF_A, DW_A1, A1_F32, A1_HI, A1_LO, 1, 1,
        XB_F32, OFF_B, DW_B1, B1_F32, B1_HI, B1_LO, 2, 1);

    // 4: stage-2 offset convs (k5 + k7)
    conv_s2_kernel<<<dim3(1024), 256, 23616, stream>>>(cvs_off_b, cs_off_b);

    // 5: stage-2 fused precompute+sampling
    sample_kernel<5, 7, 0><<<dim3(4096), 256, 0, stream>>>(
        A1_F32, OFF_A, DW_A2, A2_F32, 0, 0, 6, 3,
        B1_F32, OFF_B, DW_B2, B2_F32, 0, 0, 9, 3);

    // 6: 1x1 convs + gating multiply
    final_kernel<<<dim3(64, 4, 2), 256, 0, stream>>>(
        x, A2_F32, B2_F32, conv1_w, conv1_b, conv2_w, conv2_b, out);
}